// Round 12
// baseline (2501.261 us; speedup 1.0000x reference)
//
#include <hip/hip_runtime.h>
#include <math.h>

#define NB 8
#define NP 2048
#define KNBR 20
#define NROWS (NB*NP)      // 16384
#define SLOPEV 0.2f
#define EPSV 1e-5f

typedef short s8v __attribute__((ext_vector_type(8)));
typedef float f4v __attribute__((ext_vector_type(4)));
typedef double d4v __attribute__((ext_vector_type(4)));

__device__ __forceinline__ unsigned short f2bf(float f) {
    union { float f; unsigned u; } v; v.f = f;
    unsigned r = v.u + 0x7FFFu + ((v.u >> 16) & 1u);   // RNE
    return (unsigned short)(r >> 16);
}

// ===========================================================================
// Runtime probe of v_mfma_f64_16x16x4 lane layouts (verified working in R10).
// ===========================================================================
__global__ void mfma64_probe(int* __restrict__ tab)
{
    const int lane = threadIdx.x;          // launched with 64 threads
    d4v z = {0.0, 0.0, 0.0, 0.0};
    d4v pa = __builtin_amdgcn_mfma_f64_16x16x4f64((double)lane, 1.0, z, 0, 0, 0);
    d4v pb = __builtin_amdgcn_mfma_f64_16x16x4f64(1.0, (double)lane, z, 0, 0, 0);
    int famA = 1, famB = 1;
#pragma unroll
    for (int r = 0; r < 4; ++r) {
        int iv = (int)(pa[r] + 0.5);
        int row;
        if ((iv & 3) == 0 && iv >= 96) row = (iv - 96) >> 2;
        else { row = (iv - 6) >> 4; famA = 0; }
        int jv = (int)(pb[r] + 0.5);
        int col;
        if ((jv & 3) == 0 && jv >= 96) col = (jv - 96) >> 2;
        else { col = (jv - 6) >> 4; famB = 0; }
        tab[lane * 8 + r]     = row;
        tab[lane * 8 + 4 + r] = col;
    }
    tab[512 + lane] = famA;
    tab[576 + lane] = famB;
}

// ===========================================================================
// Fused dist + top-20, v3: barrier-free K-loop. A-strip in registers,
// B loaded DIRECTLY from global/L2 (per-batch F slab is 1-2 MB; bb=lin%8
// block swizzle pins one batch per XCD -> L2-resident). MFMA sequence,
// k-order and dist epilogue identical to R11 -> bitwise-identical distances
// -> identical selections. Only 2 barriers per 64-col tile (epilogue+merge).
// Block: 64 rows x 1024 cols (one half) of one batch; 4 waves; wave w owns
// rows [w*16, w*16+16). grid = (32, 2, NB), swizzled inside.
// ===========================================================================
template<int KD>
__global__ __launch_bounds__(256, 2) void knn_fused3(
    const double* __restrict__ F, int lda, int C,
    const double* __restrict__ xx,
    double* __restrict__ tmpv, int* __restrict__ tmpc,
    const int* __restrict__ tab)
{
    __shared__ double Tile[64][65];
    __shared__ double thr[64];
    __shared__ unsigned msk[64][2];

    const int tid = threadIdx.x;
    const int wave = tid >> 6, lane = tid & 63;
    const int lin  = (blockIdx.z * gridDim.y + blockIdx.y) * gridDim.x + blockIdx.x;
    const int bb   = lin & 7;                 // batch == XCD (round-robin dispatch)
    const int rest = lin >> 3;
    const int half = rest >> 5;
    const int r0   = (rest & 31) * 64;
    const int cbase = half * 1024;
    const double* Fb  = F  + (size_t)bb * NP * lda;
    const double* xxb = xx + (size_t)bb * NP;

    int rT[4], cT[4];
#pragma unroll
    for (int r = 0; r < 4; ++r) { rT[r] = tab[lane * 8 + r]; cT[r] = tab[lane * 8 + 4 + r]; }
    const int famA = tab[512];
    const int famB = tab[576];
    const int am = famA ? (lane & 15) : (lane >> 2);
    const int ak = famA ? (lane >> 4) : (lane & 3);
    const int bn = famB ? (lane & 15) : (lane >> 2);
    const int bk = famB ? (lane >> 4) : (lane & 3);

    // register-resident A strip for this lane's row
    const int arow = r0 + wave * 16 + am;
    double areg[KD / 4];
#pragma unroll
    for (int j = 0; j < KD / 4; ++j) {
        const int k = j * 4 + ak;
        areg[j] = (k < C) ? Fb[(size_t)arow * lda + k] : 0.0;
    }
    double xr4[4];
#pragma unroll
    for (int rg = 0; rg < 4; ++rg)
        xr4[rg] = xxb[r0 + wave * 16 + rT[rg]];

    double kv[KNBR];
    int    ki[KNBR];
#pragma unroll
    for (int q = 0; q < KNBR; ++q) { kv[q] = -INFINITY; ki[q] = 0; }
    if (tid < 64) { thr[tid] = -INFINITY; msk[tid][0] = 0u; msk[tid][1] = 0u; }
    __syncthreads();

    for (int ct = 0; ct < 16; ++ct) {
        const int c0 = cbase + ct * 64;
        d4v acc[4];
#pragma unroll
        for (int nt = 0; nt < 4; ++nt) acc[nt] = (d4v){0.0, 0.0, 0.0, 0.0};

        const double* bp0 = Fb + (size_t)(c0      + bn) * lda;
        const double* bp1 = Fb + (size_t)(c0 + 16 + bn) * lda;
        const double* bp2 = Fb + (size_t)(c0 + 32 + bn) * lda;
        const double* bp3 = Fb + (size_t)(c0 + 48 + bn) * lda;

#pragma unroll 4
        for (int kg = 0; kg < KD / 4; ++kg) {
            const int k = kg * 4 + bk;
            double b0, b1, b2, b3;
            if (KD == 4) {                    // layer 1: C=3, guard k==3
                const bool gok = (k < C);
                b0 = gok ? bp0[k] : 0.0;
                b1 = gok ? bp1[k] : 0.0;
                b2 = gok ? bp2[k] : 0.0;
                b3 = gok ? bp3[k] : 0.0;
            } else {
                b0 = bp0[k]; b1 = bp1[k]; b2 = bp2[k]; b3 = bp3[k];
            }
            const double a = areg[kg];
            acc[0] = __builtin_amdgcn_mfma_f64_16x16x4f64(a, b0, acc[0], 0, 0, 0);
            acc[1] = __builtin_amdgcn_mfma_f64_16x16x4f64(a, b1, acc[1], 0, 0, 0);
            acc[2] = __builtin_amdgcn_mfma_f64_16x16x4f64(a, b2, acc[2], 0, 0, 0);
            acc[3] = __builtin_amdgcn_mfma_f64_16x16x4f64(a, b3, acc[3], 0, 0, 0);
        }

        // epilogue: dist + threshold test (thr stable since last merge+sync)
#pragma unroll
        for (int nt = 0; nt < 4; ++nt) {
#pragma unroll
            for (int rg = 0; rg < 4; ++rg) {
                const int rloc = wave * 16 + rT[rg];
                const int cloc = nt * 16 + cT[rg];
                const double d = (2.0 * acc[nt][rg] - xr4[rg]) - xxb[c0 + cloc];
                if (d > thr[rloc]) {
                    Tile[rloc][cloc] = d;
                    atomicOr(&msk[rloc][cloc >> 5], 1u << (cloc & 31));
                }
            }
        }
        __syncthreads();

        // merge: one thread per row (R4-verified semantics)
        if (tid < 64) {
            bool changed = false;
#pragma unroll
            for (int w2 = 0; w2 < 2; ++w2) {
                unsigned m = msk[tid][w2];
                msk[tid][w2] = 0u;
                while (m) {
                    const int b = __ffs(m) - 1;
                    m &= m - 1u;
                    const double v = Tile[tid][w2 * 32 + b];
                    if (v > kv[KNBR - 1]) {
                        const int col = c0 + w2 * 32 + b;
                        int pos = 0;
#pragma unroll
                        for (int q = 0; q < KNBR; ++q) pos += (kv[q] >= v) ? 1 : 0;
#pragma unroll
                        for (int q = KNBR - 1; q >= 0; --q) {
                            if (q > pos)       { kv[q] = kv[q - 1]; ki[q] = ki[q - 1]; }
                            else if (q == pos) { kv[q] = v;         ki[q] = col; }
                        }
                        changed = true;
                    }
                }
            }
            if (changed) thr[tid] = kv[KNBR - 1];
        }
        __syncthreads();
    }

    if (tid < 64) {
        const size_t rowg = (size_t)bb * NP + r0 + tid;
        double* vp = tmpv + (rowg * 2 + half) * KNBR;
        int*    cp = tmpc + (rowg * 2 + half) * KNBR;
#pragma unroll
        for (int q = 0; q < KNBR; ++q) { vp[q] = kv[q]; cp[q] = ki[q]; }
    }
}

// ---------------------------------------------------------------------------
// merge two sorted (val desc, col asc) top-20 halves -> final top-20 indices.
// tie -> lower col (matches jax.lax.top_k).
// ---------------------------------------------------------------------------
__global__ void merge_topk(const double* __restrict__ tmpv,
                           const int* __restrict__ tmpc,
                           int* __restrict__ out)
{
    const int row = blockIdx.x * 256 + threadIdx.x;
    if (row >= NROWS) return;
    const double* va = tmpv + (size_t)row * 2 * KNBR;
    const int*    ca = tmpc + (size_t)row * 2 * KNBR;
    const double* vb = va + KNBR;
    const int*    cb = ca + KNBR;
    const int jbase = (row / NP) * NP;
    int* op = out + (size_t)row * KNBR;
    int ia = 0, ib = 0;
#pragma unroll
    for (int q = 0; q < KNBR; ++q) {
        const double x = va[ia], y = vb[ib];
        const bool takeA = (x > y) || (x == y && ca[ia] < cb[ib]);
        if (takeA) { op[q] = jbase + ca[ia]; ++ia; }
        else       { op[q] = jbase + cb[ib]; ++ib; }
    }
}

// ===========================================================================
// fp64 MFMA GEMM (PQ, probe-driven): A(NROWSxK) * wmod^T(2OxK);
// cols [0,O)->P, [O,2O)->Q. 128x64 tile.  (unchanged from R10)
// ===========================================================================
#define DK 16
__global__ __launch_bounds__(256, 2) void gemm64(
    const double* __restrict__ A, int lda,
    const double* __restrict__ Bm, int ldb,
    double* __restrict__ P, double* __restrict__ Q, int O, int Kd,
    const int* __restrict__ tab)
{
    __shared__ double As[DK][130];
    __shared__ double Bs[DK][66];
    const int tid = threadIdx.x;
    const int wave = tid >> 6, lane = tid & 63;
    const int quad = lane >> 4, l15 = lane & 15;
    const int row0 = blockIdx.y * 128, col0 = blockIdx.x * 64;

    int rT[4], cT[4];
#pragma unroll
    for (int r = 0; r < 4; ++r) { rT[r] = tab[lane * 8 + r]; cT[r] = tab[lane * 8 + 4 + r]; }
    const int famA = tab[512];
    const int famB = tab[576];
    const int am = famA ? l15 : (lane >> 2);
    const int ak = famA ? quad : (lane & 3);
    const int bn = famB ? l15 : (lane >> 2);
    const int bk = famB ? quad : (lane & 3);

    d4v acc[2][4];
#pragma unroll
    for (int mt = 0; mt < 2; ++mt)
#pragma unroll
        for (int nt = 0; nt < 4; ++nt) acc[mt][nt] = (d4v){0.0, 0.0, 0.0, 0.0};

    const int ma = tid >> 1, ka = (tid & 1) * 8;
    const int mb = tid >> 2, kb = (tid & 3) * 4;

    for (int kc = 0; kc < Kd; kc += DK) {
        const double* ap = A + (size_t)(row0 + ma) * lda + kc + ka;
#pragma unroll
        for (int i = 0; i < 8; ++i) {
            const int k2 = kc + ka + i;
            As[ka + i][ma] = (k2 < Kd) ? ap[i] : 0.0;
        }
        const double* bp = Bm + (size_t)(col0 + mb) * ldb + kc + kb;
#pragma unroll
        for (int i = 0; i < 4; ++i) {
            const int k2 = kc + kb + i;
            Bs[kb + i][mb] = (k2 < Kd) ? bp[i] : 0.0;
        }
        __syncthreads();
#pragma unroll
        for (int kg = 0; kg < 4; ++kg) {
            const int k = kg * 4;
            double a0 = As[k + ak][wave * 32 + am];
            double a1 = As[k + ak][wave * 32 + 16 + am];
            double b0 = Bs[k + bk][bn];
            double b1 = Bs[k + bk][16 + bn];
            double b2 = Bs[k + bk][32 + bn];
            double b3 = Bs[k + bk][48 + bn];
            acc[0][0] = __builtin_amdgcn_mfma_f64_16x16x4f64(a0, b0, acc[0][0], 0, 0, 0);
            acc[0][1] = __builtin_amdgcn_mfma_f64_16x16x4f64(a0, b1, acc[0][1], 0, 0, 0);
            acc[0][2] = __builtin_amdgcn_mfma_f64_16x16x4f64(a0, b2, acc[0][2], 0, 0, 0);
            acc[0][3] = __builtin_amdgcn_mfma_f64_16x16x4f64(a0, b3, acc[0][3], 0, 0, 0);
            acc[1][0] = __builtin_amdgcn_mfma_f64_16x16x4f64(a1, b0, acc[1][0], 0, 0, 0);
            acc[1][1] = __builtin_amdgcn_mfma_f64_16x16x4f64(a1, b1, acc[1][1], 0, 0, 0);
            acc[1][2] = __builtin_amdgcn_mfma_f64_16x16x4f64(a1, b2, acc[1][2], 0, 0, 0);
            acc[1][3] = __builtin_amdgcn_mfma_f64_16x16x4f64(a1, b3, acc[1][3], 0, 0, 0);
        }
        __syncthreads();
    }

    double* dst = (col0 < O) ? P : Q;
    const int cbase = (col0 < O) ? col0 : (col0 - O);
#pragma unroll
    for (int mt = 0; mt < 2; ++mt)
#pragma unroll
        for (int nt = 0; nt < 4; ++nt) {
#pragma unroll
            for (int rg = 0; rg < 4; ++rg) {
                const int r = row0 + wave * 32 + mt * 16 + rT[rg];
                const int c = cbase + nt * 16 + cT[rg];
                dst[(size_t)r * O + c] = acc[mt][nt][rg];
            }
        }
}

// ===========================================================================
// bf16 MFMA GEMM (MLP): unchanged from R10.
// ===========================================================================
__global__ __launch_bounds__(256) void gemm_bf16(
    const float* __restrict__ A, int lda,
    const unsigned short* __restrict__ W,
    float* __restrict__ C, int ldc,
    int Kd,
    const float* __restrict__ bias,
    const float* __restrict__ a_ss)
{
    __shared__ unsigned short As[4][64][8];
    __shared__ unsigned short Bs[4][128][8];
    const int tid = threadIdx.x;
    const int wave = tid >> 6, lane = tid & 63;
    const int quad = lane >> 4, l15 = lane & 15;
    const int row0 = blockIdx.y * 64, col0 = blockIdx.x * 128;

    f4v acc[4][2];
#pragma unroll
    for (int mt = 0; mt < 4; ++mt)
#pragma unroll
        for (int nt = 0; nt < 2; ++nt) acc[mt][nt] = (f4v){0.f, 0.f, 0.f, 0.f};

    const int ar = tid >> 2, akc = tid & 3;
    const int br = tid >> 1, bkc = (tid & 1) * 2;

    for (int kc0 = 0; kc0 < Kd; kc0 += 32) {
        {
            const float* ap = A + (size_t)(row0 + ar) * lda + kc0 + akc * 8;
            float t0[8];
            *(float4*)&t0[0] = *(const float4*)ap;
            *(float4*)&t0[4] = *(const float4*)(ap + 4);
            if (a_ss) {
                const int kb = kc0 + akc * 8;
#pragma unroll
                for (int i = 0; i < 8; ++i)
                    t0[i] = fmaf(t0[i], a_ss[kb + i], a_ss[Kd + kb + i]);
            }
            unsigned short u[8];
#pragma unroll
            for (int i = 0; i < 8; ++i) u[i] = f2bf(t0[i]);
            *(uint4*)&As[akc][ar][0] = *(const uint4*)&u[0];
        }
        {
            const unsigned short* wp = W + (size_t)(col0 + br) * Kd + kc0 + bkc * 8;
            uint4 q0 = *(const uint4*)wp;
            uint4 q1 = *(const uint4*)(wp + 8);
            *(uint4*)&Bs[bkc][br][0]     = q0;
            *(uint4*)&Bs[bkc + 1][br][0] = q1;
        }
        __syncthreads();

        s8v a[4], b[2];
#pragma unroll
        for (int mt = 0; mt < 4; ++mt)
            a[mt] = *(const s8v*)&As[quad][mt * 16 + l15][0];
#pragma unroll
        for (int nt = 0; nt < 2; ++nt)
            b[nt] = *(const s8v*)&Bs[quad][wave * 32 + nt * 16 + l15][0];
#pragma unroll
        for (int mt = 0; mt < 4; ++mt)
#pragma unroll
            for (int nt = 0; nt < 2; ++nt)
                acc[mt][nt] = __builtin_amdgcn_mfma_f32_16x16x32_bf16(
                    a[mt], b[nt], acc[mt][nt], 0, 0, 0);
        __syncthreads();
    }

#pragma unroll
    for (int mt = 0; mt < 4; ++mt)
#pragma unroll
        for (int nt = 0; nt < 2; ++nt) {
            const int col = col0 + wave * 32 + nt * 16 + l15;
            const float bi = bias[col];
#pragma unroll
            for (int r = 0; r < 4; ++r) {
                const int row = row0 + mt * 16 + quad * 4 + r;
                float v = acc[mt][nt][r] + bi;
                v = fmaxf(v, 0.f);
                C[(size_t)row * ldc + col] = v;
            }
        }
}

// ===========================================================================
// fp32 GEMM (head): unchanged from R10.
// ===========================================================================
#define GBK 16
__global__ __launch_bounds__(256, 2) void gemm_f32(
    const float* __restrict__ A, int lda,
    const float* __restrict__ Bm, int ldb,
    float* __restrict__ Cm, int ldc,
    int M, int Nn, int Kd, int mode,
    const float* __restrict__ bias,
    const float* __restrict__ a_ss)
{
    __shared__ float As[GBK][132];
    __shared__ float Bs[GBK][132];
    const int tid = threadIdx.x;
    const int tx = tid & 15, ty = tid >> 4;
    const int lin = blockIdx.y * gridDim.x + blockIdx.x;
    const int bx = lin / gridDim.y;
    const int by = lin - bx * gridDim.y;
    const int row0 = by * 128, col0 = bx * 128;
    float acc[8][8];
#pragma unroll
    for (int i = 0; i < 8; ++i)
#pragma unroll
        for (int j = 0; j < 8; ++j) acc[i][j] = 0.f;

    const int m  = tid >> 1;
    const int kk = (tid & 1) * 8;

    for (int kc = 0; kc < Kd; kc += GBK) {
        const int gc = col0 + m;
        const float* ap = A  + (size_t)(row0 + m) * lda + kc + kk;
        const float* bp = Bm + (size_t)gc * ldb + kc + kk;
#pragma unroll
        for (int i = 0; i < 8; ++i) {
            const int k2 = kc + kk + i;
            float v = 0.f;
            if (k2 < Kd) {
                v = ap[i];
                if (a_ss) v = fmaf(v, a_ss[k2], a_ss[Kd + k2]);
            }
            As[kk + i][m] = v;
        }
#pragma unroll
        for (int i = 0; i < 8; ++i) {
            const int k2 = kc + kk + i;
            float v = 0.f;
            if (gc < Nn && k2 < Kd) v = bp[i];
            Bs[kk + i][m] = v;
        }
        __syncthreads();
#pragma unroll
        for (int k = 0; k < GBK; ++k) {
            float4 a0 = *(const float4*)&As[k][ty * 4];
            float4 a1 = *(const float4*)&As[k][64 + ty * 4];
            float4 b0 = *(const float4*)&Bs[k][tx * 4];
            float4 b1 = *(const float4*)&Bs[k][64 + tx * 4];
            float a[8] = {a0.x, a0.y, a0.z, a0.w, a1.x, a1.y, a1.z, a1.w};
            float b[8] = {b0.x, b0.y, b0.z, b0.w, b1.x, b1.y, b1.z, b1.w};
#pragma unroll
            for (int i = 0; i < 8; ++i)
#pragma unroll
                for (int j = 0; j < 8; ++j) acc[i][j] = fmaf(a[i], b[j], acc[i][j]);
        }
        __syncthreads();
    }

#pragma unroll
    for (int i = 0; i < 8; ++i) {
        const int row = row0 + ty * 4 + (i & 3) + ((i >> 2) << 6);
        if (row >= M) continue;
#pragma unroll
        for (int h = 0; h < 2; ++h) {
            const int c0 = col0 + tx * 4 + (h << 6);
#pragma unroll
            for (int j = 0; j < 4; ++j) {
                const int col = c0 + j;
                if (col < Nn) {
                    float t = acc[i][h * 4 + j];
                    if (mode == 2)      t = fmaxf(t + bias[col], 0.f);
                    else if (mode == 3) t = t + bias[col];
                    Cm[(size_t)row * ldc + col] = t;
                }
            }
        }
    }
}

// ---------------------------------------------------------------------------
__global__ void f2d_kernel(const float* __restrict__ in, double* __restrict__ out, long n)
{
    long t = (long)blockIdx.x * 256 + threadIdx.x;
    if (t < n) out[t] = (double)in[t];
}
__global__ void d2f_kernel(const double* __restrict__ in, float* __restrict__ out, long n)
{
    long t = (long)blockIdx.x * 256 + threadIdx.x;
    if (t < n) out[t] = (float)in[t];
}

__global__ void xx_kernel_d(const double* __restrict__ F, int lda, int C,
                            double* __restrict__ xx)
{
    int r = blockIdx.x * 256 + threadIdx.x;
    if (r >= NROWS) return;
    const double* p = F + (long)r * lda;
    double s = 0.0;
    for (int c = 0; c < C; ++c) { double v = p[c]; s = fma(v, v, s); }
    xx[r] = s;
}

__global__ void wmod_kernel_d(const float* __restrict__ w, double* __restrict__ wm,
                              int O, int C)
{
    int t = blockIdx.x * 256 + threadIdx.x;
    if (t >= O * C) return;
    int o = t / C, c = t - o * C;
    double a = (double)w[o * 2 * C + c];
    double b = (double)w[o * 2 * C + C + c];
    wm[o * C + c] = a;
    wm[(O + o) * C + c] = b - a;
}

__global__ void transpose_kernel(const float* __restrict__ in, float* __restrict__ out,
                                 int R, int C)
{
    long t = (long)blockIdx.x * 256 + threadIdx.x;
    if (t >= (long)R * C) return;
    int r = (int)(t / C), c = (int)(t - (long)r * C);
    out[(long)c * R + r] = in[t];
}

__global__ void transpose_bf(const float* __restrict__ in, unsigned short* __restrict__ out,
                             int R, int C)
{
    long t = (long)blockIdx.x * 256 + threadIdx.x;
    if (t >= (long)R * C) return;
    int r = (int)(t / C), c = (int)(t - (long)r * C);
    out[(long)c * R + r] = f2bf(in[t]);
}

// ---------------------------------------------------------------------------
// Single gather pass (P/Q split): stats + pre-BN max -> catOut. Unchanged.
// ---------------------------------------------------------------------------
__global__ __launch_bounds__(256) void edge_gather(const double* __restrict__ P,
                                                   const double* __restrict__ Q,
                                                   const int* __restrict__ idx,
                                                   int O, int shiftO,
                                                   double* __restrict__ sums,
                                                   double* __restrict__ catOut, int ldo)
{
    const int tid = threadIdx.x;
    const int o = tid & (O - 1);
    const int q = tid >> shiftO;
    const int nsub = 256 >> shiftO;
    const int lin = blockIdx.x;
    const int r0 = (lin & 7) * NP + (lin >> 3) * 16;   // XCD-batch swizzle
    double s = 0.0, ss = 0.0;
    for (int r = r0 + q; r < r0 + 16; r += nsub) {
        const double qv = Q[(size_t)r * O + o];
        const int* ip = idx + r * KNBR;
        double m = -INFINITY;
        for (int k = 0; k < KNBR; ++k) {
            const int j = ip[k];
            const double v = P[(size_t)j * O + o] + qv;
            s += v; ss = fma(v, v, ss);
            m = fmax(m, v);
        }
        catOut[(size_t)r * ldo + o] = m;
    }
    __shared__ double red[256];
    red[tid] = s; __syncthreads();
    if (q == 0) for (int qq = 1; qq < nsub; ++qq) s += red[o + (qq << shiftO)];
    __syncthreads();
    red[tid] = ss; __syncthreads();
    if (q == 0) {
        for (int qq = 1; qq < nsub; ++qq) ss += red[o + (qq << shiftO)];
        atomicAdd(&sums[o], s);
        atomicAdd(&sums[O + o], ss);
    }
}

__global__ void bn_finalize_d(const double* __restrict__ sums,
                              const float* __restrict__ g, const float* __restrict__ b,
                              double* __restrict__ ss, int O, double invCnt)
{
    int o = blockIdx.x * 256 + threadIdx.x;
    if (o >= O) return;
    double mu  = sums[o] * invCnt;
    double var = sums[O + o] * invCnt - mu * mu;
    double is  = 1.0 / sqrt(var + 1e-5);
    double sc  = (double)g[o] * is;
    ss[o] = sc;
    ss[O + o] = (double)b[o] - mu * sc;
}

__global__ __launch_bounds__(256) void bn_apply(double* __restrict__ catOut, int ldo,
                                                const double* __restrict__ ssb,
                                                int O, int shiftO,
                                                const double* __restrict__ P,
                                                const double* __restrict__ Q,
                                                const int* __restrict__ idx)
{
    const int t = blockIdx.x * 256 + threadIdx.x;
    const int o = t & (O - 1);
    const int r = t >> shiftO;
    const double sc = ssb[o], sh = ssb[O + o];
    double v = catOut[(size_t)r * ldo + o];
    if (sc < 0.0) {                       // rare path: min instead of max
        const double qv = Q[(size_t)r * O + o];
        const int* ip = idx + r * KNBR;
        double m = INFINITY;
        for (int k = 0; k < KNBR; ++k)
            m = fmin(m, P[(size_t)ip[k] * O + o] + qv);
        v = m;
    }
    double u = fma(v, sc, sh);
    u = u > 0.0 ? u : 0.2 * u;
    catOut[(size_t)r * ldo + o] = u;
}

// ---------------------------------------------------------------------------
__global__ void col_stats(const float* __restrict__ Y, int ncol,
                          float* __restrict__ sums)
{
    int c  = blockIdx.x * 128 + threadIdx.x;
    int r0 = blockIdx.y * 256;
    float s = 0.f, ss = 0.f;
    for (int r = r0; r < r0 + 256; ++r) {
        float v = Y[(long)r * ncol + c];
        s += v; ss = fmaf(v, v, ss);
    }
    atomicAdd(&sums[c], s);
    atomicAdd(&sums[ncol + c], ss);
}

__global__ void bn_finalize_f(const float* __restrict__ sums,
                              const float* __restrict__ g, const float* __restrict__ b,
                              float* __restrict__ ss, int O, float invCnt)
{
    int o = blockIdx.x * 256 + threadIdx.x;
    if (o >= O) return;
    float mu  = sums[o] * invCnt;
    float var = sums[O + o] * invCnt - mu * mu;
    float is  = rsqrtf(var + EPSV);
    float sc  = g[o] * is;
    ss[o] = sc;
    ss[O + o] = b[o] - mu * sc;
}

__global__ __launch_bounds__(256) void log_softmax_kernel(float* __restrict__ Y)
{
    const int lane = threadIdx.x & 63;
    const int row  = blockIdx.x * 4 + (threadIdx.x >> 6);
    float v = -INFINITY;
    if (lane < 50) v = Y[(long)row * 50 + lane];
    float mx = v;
#pragma unroll
    for (int off = 32; off >= 1; off >>= 1) mx = fmaxf(mx, __shfl_xor(mx, off, 64));
    float e = (lane < 50) ? expf(v - mx) : 0.f;
    float s = e;
#pragma unroll
    for (int off = 32; off >= 1; off >>= 1) s += __shfl_xor(s, off, 64);
    float l = logf(s) + mx;
    if (lane < 50) Y[(long)row * 50 + lane] = v - l;
}

// ===========================================================================
extern "C" void kernel_launch(void* const* d_in, const int* in_sizes, int n_in,
                              void* d_out, int out_size, void* d_ws, size_t ws_size,
                              hipStream_t stream)
{
    const float* x   = (const float*)d_in[0];
    const float* w[4]  = {(const float*)d_in[4], (const float*)d_in[7],
                          (const float*)d_in[10], (const float*)d_in[13]};
    const float* g[4]  = {(const float*)d_in[5], (const float*)d_in[8],
                          (const float*)d_in[11], (const float*)d_in[14]};
    const float* bb[4] = {(const float*)d_in[6], (const float*)d_in[9],
                          (const float*)d_in[12], (const float*)d_in[15]};
    const float* lw1 = (const float*)d_in[16]; const float* lb1 = (const float*)d_in[17];
    const float* lg1 = (const float*)d_in[18]; const float* lbb1 = (const float*)d_in[19];
    const float* mw1 = (const float*)d_in[20]; const float* mb1 = (const float*)d_in[21];
    const float* mg1 = (const float*)d_in[22]; const float* mbb1 = (const float*)d_in[23];
    const float* mw2 = (const float*)d_in[24]; const float* mb2 = (const float*)d_in[25];
    const float* mg2 = (const float*)d_in[26]; const float* mbb2 = (const float*)d_in[27];
    const float* hw  = (const float*)d_in[28]; const float* hb  = (const float*)d_in[29];
    float* out = (float*)d_out;

    // ---- workspace layout (bytes) ----
    char* base = (char*)d_ws;
    double* catD = (double*)base;                       // 64 MB
    char*  un    = base + 67108864;                     // 64 MB union region
    double* tmpv = (double*)un;                         // 16384*2*20*8 = 5.24 MB
    int*    tmpc = (int*)(un + 5242880);                // 2.62 MB (dead before PQ)
    double* Pb   = (double*)un;                         // P: up to 32 MB (after merge)
    double* Qb   = (double*)(un + 33554432);            // Q: up to 32 MB
    float* cat32 = (float*)un;                          // 32 MB (MLP phase)
    float* Y2    = (float*)(un + 33554432);             // 16 MB
    float* Y3    = (float*)(un + 50331648);             // 8 MB
    unsigned short* lw1Tb = (unsigned short*)(un + 58720256);  // 1 MB
    unsigned short* mw1Tb = (unsigned short*)(un + 59768832);  // 512 KB
    unsigned short* mw2Tb = (unsigned short*)(un + 60293120);  // 64 KB
    float* hwT   = (float*)(un + 60358656);             // 25.6 KB (fp32)
    float* Y1    = (float*)base;                        // aliases catD (dead after d2f)
    char* tail = base + 2u * 67108864u;
    int*    idxb  = (int*)tail;                         // 1.25 MB
    double* xD    = (double*)(tail + 1310720);          // 384 KB
    double* xxD   = (double*)(tail + 1703936);          // 128 KB
    double* wmodD = (double*)(tail + 1835008);          // 512 KB
    double* sumsD = (double*)(tail + 2359296);          // 8 KB
    double* ssbD  = (double*)(tail + 2367488);          // 8 KB
    float*  sumsF = (float*)(tail + 2375680);           // 8 KB
    float*  ssbF  = (float*)(tail + 2383872);           // 8 KB
    int*    mtab  = (int*)(tail + 2392064);             // 2.5 KB probe table

    // ---- fp64-MFMA layout probe (1 wave) ----
    mfma64_probe<<<1, 64, 0, stream>>>(mtab);

    // ---- x -> fp64 ----
    f2d_kernel<<<(NROWS * 3 + 255) / 256, 256, 0, stream>>>(x, xD, (long)NROWS * 3);

    // ---- 4 EdgeConv layers (all fp64) ----
    const double* Fin[4] = {xD, catD + 0, catD + 64, catD + 128};
    const int   ldaL[4] = {3, 512, 512, 512};
    const int   CL[4]   = {3, 64, 64, 128};
    const int   OL[4]   = {64, 64, 128, 256};
    const int   coff[4] = {0, 64, 128, 256};

    for (int l = 0; l < 4; ++l) {
        const double* F = Fin[l];
        const int lda = ldaL[l], C = CL[l], O = OL[l];
        const int shiftO = (O == 64) ? 6 : (O == 128) ? 7 : 8;

        wmod_kernel_d<<<(O * C + 255) / 256, 256, 0, stream>>>(w[l], wmodD, O, C);
        xx_kernel_d<<<NROWS / 256, 256, 0, stream>>>(F, lda, C, xxD);

        // fused dist + top-20 (no D materialization, barrier-free K-loop)
        dim3 kg(NP / 64, 2, NB);
        if (C == 3)
            knn_fused3<4><<<kg, 256, 0, stream>>>(F, lda, C, xxD, tmpv, tmpc, mtab);
        else if (C == 64)
            knn_fused3<64><<<kg, 256, 0, stream>>>(F, lda, C, xxD, tmpv, tmpc, mtab);
        else
            knn_fused3<128><<<kg, 256, 0, stream>>>(F, lda, C, xxD, tmpv, tmpc, mtab);
        merge_topk<<<NROWS / 256, 256, 0, stream>>>(tmpv, tmpc, idxb);

        gemm64<<<dim3((2 * O) / 64, NROWS / 128), 256, 0, stream>>>(
            F, lda, wmodD, C, Pb, Qb, O, C, mtab);

        hipMemsetAsync(sumsD, 0, 2 * O * sizeof(double), stream);
        edge_gather<<<NROWS / 16, 256, 0, stream>>>(Pb, Qb, idxb, O, shiftO, sumsD,
                                                    catD + coff[l], 512);
        bn_finalize_d<<<(O + 255) / 256, 256, 0, stream>>>(sumsD, g[l], bb[l], ssbD, O,
                                                           1.0 / ((double)NROWS * KNBR));
        bn_apply<<<(NROWS * O) / 256, 256, 0, stream>>>(catD + coff[l], 512, ssbD,
                                                        O, shiftO, Pb, Qb, idxb);
    }

    // ---- cat fp64 -> fp32 (catD region becomes free -> Y1) ----
    d2f_kernel<<<((long)NROWS * 512 + 255) / 256, 256, 0, stream>>>(catD, cat32, (long)NROWS * 512);

    // ---- weight transposes (MLP -> bf16, head -> fp32) ----
    transpose_bf<<<(512 * 1024 + 255) / 256, 256, 0, stream>>>(lw1, lw1Tb, 512, 1024);
    transpose_bf<<<(1024 * 256 + 255) / 256, 256, 0, stream>>>(mw1, mw1Tb, 1024, 256);
    transpose_bf<<<(256 * 128 + 255) / 256, 256, 0, stream>>>(mw2, mw2Tb, 256, 128);
    transpose_kernel<<<(128 * 50 + 255) / 256, 256, 0, stream>>>(hw, hwT, 128, 50);

    // ---- MLP: bf16 MFMA GEMMs, fp32 accumulate ----
    {
        gemm_bf16<<<dim3(1024 / 128, NROWS / 64), 256, 0, stream>>>(
            cat32, 512, lw1Tb, Y1, 1024, 512, lb1, nullptr);
        hipMemsetAsync(sumsF, 0, 2 * 1024 * sizeof(float), stream);
        col_stats<<<dim3(1024 / 128, 64), 128, 0, stream>>>(Y1, 1024, sumsF);
        bn_finalize_f<<<4, 256, 0, stream>>>(sumsF, lg1, lbb1, ssbF, 1024, 1.f / NROWS);
    }
    {
        gemm_bf16<<<dim3(256 / 128, NROWS / 64), 256, 0, stream>>>(
            Y1, 1024, mw1Tb, Y2, 256, 1024, mb1, ssbF);
        hipMemsetAsync(sumsF, 0, 2 * 256 * sizeof(float), stream);
        col_stats<<<dim3(256 / 128, 64), 128, 0, stream>>>(Y2, 256, sumsF);
        bn_finalize_f<<<1, 256, 0, stream>>>(sumsF, mg1, mbb1, ssbF, 256, 1.f / NROWS);
    }
    {
        gemm_bf16<<<dim3(128 / 128, NROWS / 64), 256, 0, stream>>>(
            Y2, 256, mw2Tb, Y3, 128, 256, mb2, ssbF);
        hipMemsetAsync(sumsF, 0, 2 * 128 * sizeof(float), stream);
        col_stats<<<dim3(1, 64), 128, 0, stream>>>(Y3, 128, sumsF);
        bn_finalize_f<<<1, 256, 0, stream>>>(sumsF, mg2, mbb2, ssbF, 128, 1.f / NROWS);
    }
    {
        dim3 gg(1, NROWS / 128);
        gemm_f32<<<gg, 256, 0, stream>>>(Y3, 128, hwT, 128, out, 50,
                                         NROWS, 50, 128, 3, hb, ssbF);
        log_softmax_kernel<<<NROWS / 4, 256, 0, stream>>>(out);
    }
}

// Round 13
// 1922.129 us; speedup vs baseline: 1.3013x; 1.3013x over previous
//
#include <hip/hip_runtime.h>
#include <math.h>

#define NB 8
#define NP 2048
#define KNBR 20
#define NROWS (NB*NP)      // 16384
#define SLOPEV 0.2f
#define EPSV 1e-5f

typedef short s8v __attribute__((ext_vector_type(8)));
typedef float f4v __attribute__((ext_vector_type(4)));
typedef double d4v __attribute__((ext_vector_type(4)));

__device__ __forceinline__ unsigned short f2bf(float f) {
    union { float f; unsigned u; } v; v.f = f;
    unsigned r = v.u + 0x7FFFu + ((v.u >> 16) & 1u);   // RNE
    return (unsigned short)(r >> 16);
}

// ===========================================================================
// Runtime probe of v_mfma_f64_16x16x4 lane layouts (verified working in R10).
// ===========================================================================
__global__ void mfma64_probe(int* __restrict__ tab)
{
    const int lane = threadIdx.x;          // launched with 64 threads
    d4v z = {0.0, 0.0, 0.0, 0.0};
    d4v pa = __builtin_amdgcn_mfma_f64_16x16x4f64((double)lane, 1.0, z, 0, 0, 0);
    d4v pb = __builtin_amdgcn_mfma_f64_16x16x4f64(1.0, (double)lane, z, 0, 0, 0);
    int famA = 1, famB = 1;
#pragma unroll
    for (int r = 0; r < 4; ++r) {
        int iv = (int)(pa[r] + 0.5);
        int row;
        if ((iv & 3) == 0 && iv >= 96) row = (iv - 96) >> 2;
        else { row = (iv - 6) >> 4; famA = 0; }
        int jv = (int)(pb[r] + 0.5);
        int col;
        if ((jv & 3) == 0 && jv >= 96) col = (jv - 96) >> 2;
        else { col = (jv - 6) >> 4; famB = 0; }
        tab[lane * 8 + r]     = row;
        tab[lane * 8 + 4 + r] = col;
    }
    tab[512 + lane] = famA;
    tab[576 + lane] = famB;
}

// ===========================================================================
// Fused dist + top-20, v2b (R11 structure, CH=32): MFMA micro, probe-driven;
// LDS-staged B shared by 4 waves (R12 showed direct-global B loses 4x);
// CH doubled 16->32 halves the barrier count (10/tile vs 18 at K=128).
// MFMA k-group order identical to R11 -> bitwise-identical distances.
// Block: 64 rows x 1024 cols (one half) of one batch; 4 waves; wave w owns
// rows [w*16, w*16+16). grid = (32 row-groups, 2 halves, NB batches).
// ===========================================================================
template<int KD>
__global__ __launch_bounds__(256, 2) void knn_fused2(
    const double* __restrict__ F, int lda, int C,
    const double* __restrict__ xx,
    double* __restrict__ tmpv, int* __restrict__ tmpc,
    const int* __restrict__ tab)
{
    constexpr int CH = (KD < 16) ? KD : 32;
    __shared__ double Bs[CH][66];
    __shared__ double Tile[64][65];
    __shared__ double thr[64];
    __shared__ unsigned msk[64][2];

    const int tid = threadIdx.x;
    const int wave = tid >> 6, lane = tid & 63;
    const int bb    = blockIdx.z;
    const int half  = blockIdx.y;
    const int r0    = blockIdx.x * 64;
    const int cbase = half * 1024;
    const double* Fb  = F  + (size_t)bb * NP * lda;
    const double* xxb = xx + (size_t)bb * NP;

    int rT[4], cT[4];
#pragma unroll
    for (int r = 0; r < 4; ++r) { rT[r] = tab[lane * 8 + r]; cT[r] = tab[lane * 8 + 4 + r]; }
    const int famA = tab[512];
    const int famB = tab[576];
    const int am = famA ? (lane & 15) : (lane >> 2);
    const int ak = famA ? (lane >> 4) : (lane & 3);
    const int bn = famB ? (lane & 15) : (lane >> 2);
    const int bk = famB ? (lane >> 4) : (lane & 3);

    // register-resident A strip for this lane's row
    const int arow = r0 + wave * 16 + am;
    double areg[KD / 4];
#pragma unroll
    for (int j = 0; j < KD / 4; ++j) {
        const int k = j * 4 + ak;
        areg[j] = (k < C) ? Fb[(size_t)arow * lda + k] : 0.0;
    }
    double xr4[4];
#pragma unroll
    for (int rg = 0; rg < 4; ++rg)
        xr4[rg] = xxb[r0 + wave * 16 + rT[rg]];

    double kv[KNBR];
    int    ki[KNBR];
#pragma unroll
    for (int q = 0; q < KNBR; ++q) { kv[q] = -INFINITY; ki[q] = 0; }
    if (tid < 64) { thr[tid] = -INFINITY; msk[tid][0] = 0u; msk[tid][1] = 0u; }
    __syncthreads();

    for (int ct = 0; ct < 16; ++ct) {
        const int c0 = cbase + ct * 64;
        d4v acc[4];
#pragma unroll
        for (int nt = 0; nt < 4; ++nt) acc[nt] = (d4v){0.0, 0.0, 0.0, 0.0};

#pragma unroll
        for (int kc = 0; kc < KD; kc += CH) {
            {   // stage B: 64 cols x CH k
                const int col = tid >> 2;
                const int kb0 = (tid & 3) * (CH / 4);
                const double* bp = Fb + (size_t)(c0 + col) * lda + kc + kb0;
#pragma unroll
                for (int i = 0; i < CH / 4; ++i) {
                    const int k2 = kc + kb0 + i;
                    Bs[kb0 + i][col] = (k2 < C) ? bp[i] : 0.0;
                }
            }
            __syncthreads();
#pragma unroll
            for (int kg = 0; kg < CH / 4; ++kg) {
                const double a  = areg[kc / 4 + kg];
                const double b0 = Bs[kg * 4 + bk][bn];
                const double b1 = Bs[kg * 4 + bk][16 + bn];
                const double b2 = Bs[kg * 4 + bk][32 + bn];
                const double b3 = Bs[kg * 4 + bk][48 + bn];
                acc[0] = __builtin_amdgcn_mfma_f64_16x16x4f64(a, b0, acc[0], 0, 0, 0);
                acc[1] = __builtin_amdgcn_mfma_f64_16x16x4f64(a, b1, acc[1], 0, 0, 0);
                acc[2] = __builtin_amdgcn_mfma_f64_16x16x4f64(a, b2, acc[2], 0, 0, 0);
                acc[3] = __builtin_amdgcn_mfma_f64_16x16x4f64(a, b3, acc[3], 0, 0, 0);
            }
            __syncthreads();
        }

        // epilogue: dist + threshold test (thr stable since last merge+sync)
#pragma unroll
        for (int nt = 0; nt < 4; ++nt) {
#pragma unroll
            for (int rg = 0; rg < 4; ++rg) {
                const int rloc = wave * 16 + rT[rg];
                const int cloc = nt * 16 + cT[rg];
                const double d = (2.0 * acc[nt][rg] - xr4[rg]) - xxb[c0 + cloc];
                if (d > thr[rloc]) {
                    Tile[rloc][cloc] = d;
                    atomicOr(&msk[rloc][cloc >> 5], 1u << (cloc & 31));
                }
            }
        }
        __syncthreads();

        // merge: one thread per row (R4-verified semantics)
        if (tid < 64) {
            bool changed = false;
#pragma unroll
            for (int w2 = 0; w2 < 2; ++w2) {
                unsigned m = msk[tid][w2];
                msk[tid][w2] = 0u;
                while (m) {
                    const int b = __ffs(m) - 1;
                    m &= m - 1u;
                    const double v = Tile[tid][w2 * 32 + b];
                    if (v > kv[KNBR - 1]) {
                        const int col = c0 + w2 * 32 + b;
                        int pos = 0;
#pragma unroll
                        for (int q = 0; q < KNBR; ++q) pos += (kv[q] >= v) ? 1 : 0;
#pragma unroll
                        for (int q = KNBR - 1; q >= 0; --q) {
                            if (q > pos)       { kv[q] = kv[q - 1]; ki[q] = ki[q - 1]; }
                            else if (q == pos) { kv[q] = v;         ki[q] = col; }
                        }
                        changed = true;
                    }
                }
            }
            if (changed) thr[tid] = kv[KNBR - 1];
        }
        __syncthreads();
    }

    if (tid < 64) {
        const size_t rowg = (size_t)bb * NP + r0 + tid;
        double* vp = tmpv + (rowg * 2 + half) * KNBR;
        int*    cp = tmpc + (rowg * 2 + half) * KNBR;
#pragma unroll
        for (int q = 0; q < KNBR; ++q) { vp[q] = kv[q]; cp[q] = ki[q]; }
    }
}

// ---------------------------------------------------------------------------
// merge two sorted (val desc, col asc) top-20 halves -> final top-20 indices.
// tie -> lower col (matches jax.lax.top_k).
// ---------------------------------------------------------------------------
__global__ void merge_topk(const double* __restrict__ tmpv,
                           const int* __restrict__ tmpc,
                           int* __restrict__ out)
{
    const int row = blockIdx.x * 256 + threadIdx.x;
    if (row >= NROWS) return;
    const double* va = tmpv + (size_t)row * 2 * KNBR;
    const int*    ca = tmpc + (size_t)row * 2 * KNBR;
    const double* vb = va + KNBR;
    const int*    cb = ca + KNBR;
    const int jbase = (row / NP) * NP;
    int* op = out + (size_t)row * KNBR;
    int ia = 0, ib = 0;
#pragma unroll
    for (int q = 0; q < KNBR; ++q) {
        const double x = va[ia], y = vb[ib];
        const bool takeA = (x > y) || (x == y && ca[ia] < cb[ib]);
        if (takeA) { op[q] = jbase + ca[ia]; ++ia; }
        else       { op[q] = jbase + cb[ib]; ++ib; }
    }
}

// ===========================================================================
// fp64 MFMA GEMM (PQ, probe-driven): A(NROWSxK) * wmod^T(2OxK);
// cols [0,O)->P, [O,2O)->Q. 128x64 tile.  (unchanged from R10)
// ===========================================================================
#define DK 16
__global__ __launch_bounds__(256, 2) void gemm64(
    const double* __restrict__ A, int lda,
    const double* __restrict__ Bm, int ldb,
    double* __restrict__ P, double* __restrict__ Q, int O, int Kd,
    const int* __restrict__ tab)
{
    __shared__ double As[DK][130];
    __shared__ double Bs[DK][66];
    const int tid = threadIdx.x;
    const int wave = tid >> 6, lane = tid & 63;
    const int quad = lane >> 4, l15 = lane & 15;
    const int row0 = blockIdx.y * 128, col0 = blockIdx.x * 64;

    int rT[4], cT[4];
#pragma unroll
    for (int r = 0; r < 4; ++r) { rT[r] = tab[lane * 8 + r]; cT[r] = tab[lane * 8 + 4 + r]; }
    const int famA = tab[512];
    const int famB = tab[576];
    const int am = famA ? l15 : (lane >> 2);
    const int ak = famA ? quad : (lane & 3);
    const int bn = famB ? l15 : (lane >> 2);
    const int bk = famB ? quad : (lane & 3);

    d4v acc[2][4];
#pragma unroll
    for (int mt = 0; mt < 2; ++mt)
#pragma unroll
        for (int nt = 0; nt < 4; ++nt) acc[mt][nt] = (d4v){0.0, 0.0, 0.0, 0.0};

    const int ma = tid >> 1, ka = (tid & 1) * 8;
    const int mb = tid >> 2, kb = (tid & 3) * 4;

    for (int kc = 0; kc < Kd; kc += DK) {
        const double* ap = A + (size_t)(row0 + ma) * lda + kc + ka;
#pragma unroll
        for (int i = 0; i < 8; ++i) {
            const int k2 = kc + ka + i;
            As[ka + i][ma] = (k2 < Kd) ? ap[i] : 0.0;
        }
        const double* bp = Bm + (size_t)(col0 + mb) * ldb + kc + kb;
#pragma unroll
        for (int i = 0; i < 4; ++i) {
            const int k2 = kc + kb + i;
            Bs[kb + i][mb] = (k2 < Kd) ? bp[i] : 0.0;
        }
        __syncthreads();
#pragma unroll
        for (int kg = 0; kg < 4; ++kg) {
            const int k = kg * 4;
            double a0 = As[k + ak][wave * 32 + am];
            double a1 = As[k + ak][wave * 32 + 16 + am];
            double b0 = Bs[k + bk][bn];
            double b1 = Bs[k + bk][16 + bn];
            double b2 = Bs[k + bk][32 + bn];
            double b3 = Bs[k + bk][48 + bn];
            acc[0][0] = __builtin_amdgcn_mfma_f64_16x16x4f64(a0, b0, acc[0][0], 0, 0, 0);
            acc[0][1] = __builtin_amdgcn_mfma_f64_16x16x4f64(a0, b1, acc[0][1], 0, 0, 0);
            acc[0][2] = __builtin_amdgcn_mfma_f64_16x16x4f64(a0, b2, acc[0][2], 0, 0, 0);
            acc[0][3] = __builtin_amdgcn_mfma_f64_16x16x4f64(a0, b3, acc[0][3], 0, 0, 0);
            acc[1][0] = __builtin_amdgcn_mfma_f64_16x16x4f64(a1, b0, acc[1][0], 0, 0, 0);
            acc[1][1] = __builtin_amdgcn_mfma_f64_16x16x4f64(a1, b1, acc[1][1], 0, 0, 0);
            acc[1][2] = __builtin_amdgcn_mfma_f64_16x16x4f64(a1, b2, acc[1][2], 0, 0, 0);
            acc[1][3] = __builtin_amdgcn_mfma_f64_16x16x4f64(a1, b3, acc[1][3], 0, 0, 0);
        }
        __syncthreads();
    }

    double* dst = (col0 < O) ? P : Q;
    const int cbase = (col0 < O) ? col0 : (col0 - O);
#pragma unroll
    for (int mt = 0; mt < 2; ++mt)
#pragma unroll
        for (int nt = 0; nt < 4; ++nt) {
#pragma unroll
            for (int rg = 0; rg < 4; ++rg) {
                const int r = row0 + wave * 32 + mt * 16 + rT[rg];
                const int c = cbase + nt * 16 + cT[rg];
                dst[(size_t)r * O + c] = acc[mt][nt][rg];
            }
        }
}

// ===========================================================================
// bf16 MFMA GEMM (MLP): unchanged from R10.
// ===========================================================================
__global__ __launch_bounds__(256) void gemm_bf16(
    const float* __restrict__ A, int lda,
    const unsigned short* __restrict__ W,
    float* __restrict__ C, int ldc,
    int Kd,
    const float* __restrict__ bias,
    const float* __restrict__ a_ss)
{
    __shared__ unsigned short As[4][64][8];
    __shared__ unsigned short Bs[4][128][8];
    const int tid = threadIdx.x;
    const int wave = tid >> 6, lane = tid & 63;
    const int quad = lane >> 4, l15 = lane & 15;
    const int row0 = blockIdx.y * 64, col0 = blockIdx.x * 128;

    f4v acc[4][2];
#pragma unroll
    for (int mt = 0; mt < 4; ++mt)
#pragma unroll
        for (int nt = 0; nt < 2; ++nt) acc[mt][nt] = (f4v){0.f, 0.f, 0.f, 0.f};

    const int ar = tid >> 2, akc = tid & 3;
    const int br = tid >> 1, bkc = (tid & 1) * 2;

    for (int kc0 = 0; kc0 < Kd; kc0 += 32) {
        {
            const float* ap = A + (size_t)(row0 + ar) * lda + kc0 + akc * 8;
            float t0[8];
            *(float4*)&t0[0] = *(const float4*)ap;
            *(float4*)&t0[4] = *(const float4*)(ap + 4);
            if (a_ss) {
                const int kb = kc0 + akc * 8;
#pragma unroll
                for (int i = 0; i < 8; ++i)
                    t0[i] = fmaf(t0[i], a_ss[kb + i], a_ss[Kd + kb + i]);
            }
            unsigned short u[8];
#pragma unroll
            for (int i = 0; i < 8; ++i) u[i] = f2bf(t0[i]);
            *(uint4*)&As[akc][ar][0] = *(const uint4*)&u[0];
        }
        {
            const unsigned short* wp = W + (size_t)(col0 + br) * Kd + kc0 + bkc * 8;
            uint4 q0 = *(const uint4*)wp;
            uint4 q1 = *(const uint4*)(wp + 8);
            *(uint4*)&Bs[bkc][br][0]     = q0;
            *(uint4*)&Bs[bkc + 1][br][0] = q1;
        }
        __syncthreads();

        s8v a[4], b[2];
#pragma unroll
        for (int mt = 0; mt < 4; ++mt)
            a[mt] = *(const s8v*)&As[quad][mt * 16 + l15][0];
#pragma unroll
        for (int nt = 0; nt < 2; ++nt)
            b[nt] = *(const s8v*)&Bs[quad][wave * 32 + nt * 16 + l15][0];
#pragma unroll
        for (int mt = 0; mt < 4; ++mt)
#pragma unroll
            for (int nt = 0; nt < 2; ++nt)
                acc[mt][nt] = __builtin_amdgcn_mfma_f32_16x16x32_bf16(
                    a[mt], b[nt], acc[mt][nt], 0, 0, 0);
        __syncthreads();
    }

#pragma unroll
    for (int mt = 0; mt < 4; ++mt)
#pragma unroll
        for (int nt = 0; nt < 2; ++nt) {
            const int col = col0 + wave * 32 + nt * 16 + l15;
            const float bi = bias[col];
#pragma unroll
            for (int r = 0; r < 4; ++r) {
                const int row = row0 + mt * 16 + quad * 4 + r;
                float v = acc[mt][nt][r] + bi;
                v = fmaxf(v, 0.f);
                C[(size_t)row * ldc + col] = v;
            }
        }
}

// ===========================================================================
// fp32 GEMM (head): unchanged from R10.
// ===========================================================================
#define GBK 16
__global__ __launch_bounds__(256, 2) void gemm_f32(
    const float* __restrict__ A, int lda,
    const float* __restrict__ Bm, int ldb,
    float* __restrict__ Cm, int ldc,
    int M, int Nn, int Kd, int mode,
    const float* __restrict__ bias,
    const float* __restrict__ a_ss)
{
    __shared__ float As[GBK][132];
    __shared__ float Bs[GBK][132];
    const int tid = threadIdx.x;
    const int tx = tid & 15, ty = tid >> 4;
    const int lin = blockIdx.y * gridDim.x + blockIdx.x;
    const int bx = lin / gridDim.y;
    const int by = lin - bx * gridDim.y;
    const int row0 = by * 128, col0 = bx * 128;
    float acc[8][8];
#pragma unroll
    for (int i = 0; i < 8; ++i)
#pragma unroll
        for (int j = 0; j < 8; ++j) acc[i][j] = 0.f;

    const int m  = tid >> 1;
    const int kk = (tid & 1) * 8;

    for (int kc = 0; kc < Kd; kc += GBK) {
        const int gc = col0 + m;
        const float* ap = A  + (size_t)(row0 + m) * lda + kc + kk;
        const float* bp = Bm + (size_t)gc * ldb + kc + kk;
#pragma unroll
        for (int i = 0; i < 8; ++i) {
            const int k2 = kc + kk + i;
            float v = 0.f;
            if (k2 < Kd) {
                v = ap[i];
                if (a_ss) v = fmaf(v, a_ss[k2], a_ss[Kd + k2]);
            }
            As[kk + i][m] = v;
        }
#pragma unroll
        for (int i = 0; i < 8; ++i) {
            const int k2 = kc + kk + i;
            float v = 0.f;
            if (gc < Nn && k2 < Kd) v = bp[i];
            Bs[kk + i][m] = v;
        }
        __syncthreads();
#pragma unroll
        for (int k = 0; k < GBK; ++k) {
            float4 a0 = *(const float4*)&As[k][ty * 4];
            float4 a1 = *(const float4*)&As[k][64 + ty * 4];
            float4 b0 = *(const float4*)&Bs[k][tx * 4];
            float4 b1 = *(const float4*)&Bs[k][64 + tx * 4];
            float a[8] = {a0.x, a0.y, a0.z, a0.w, a1.x, a1.y, a1.z, a1.w};
            float b[8] = {b0.x, b0.y, b0.z, b0.w, b1.x, b1.y, b1.z, b1.w};
#pragma unroll
            for (int i = 0; i < 8; ++i)
#pragma unroll
                for (int j = 0; j < 8; ++j) acc[i][j] = fmaf(a[i], b[j], acc[i][j]);
        }
        __syncthreads();
    }

#pragma unroll
    for (int i = 0; i < 8; ++i) {
        const int row = row0 + ty * 4 + (i & 3) + ((i >> 2) << 6);
        if (row >= M) continue;
#pragma unroll
        for (int h = 0; h < 2; ++h) {
            const int c0 = col0 + tx * 4 + (h << 6);
#pragma unroll
            for (int j = 0; j < 4; ++j) {
                const int col = c0 + j;
                if (col < Nn) {
                    float t = acc[i][h * 4 + j];
                    if (mode == 2)      t = fmaxf(t + bias[col], 0.f);
                    else if (mode == 3) t = t + bias[col];
                    Cm[(size_t)row * ldc + col] = t;
                }
            }
        }
    }
}

// ---------------------------------------------------------------------------
__global__ void f2d_kernel(const float* __restrict__ in, double* __restrict__ out, long n)
{
    long t = (long)blockIdx.x * 256 + threadIdx.x;
    if (t < n) out[t] = (double)in[t];
}
__global__ void d2f_kernel(const double* __restrict__ in, float* __restrict__ out, long n)
{
    long t = (long)blockIdx.x * 256 + threadIdx.x;
    if (t < n) out[t] = (float)in[t];
}

__global__ void xx_kernel_d(const double* __restrict__ F, int lda, int C,
                            double* __restrict__ xx)
{
    int r = blockIdx.x * 256 + threadIdx.x;
    if (r >= NROWS) return;
    const double* p = F + (long)r * lda;
    double s = 0.0;
    for (int c = 0; c < C; ++c) { double v = p[c]; s = fma(v, v, s); }
    xx[r] = s;
}

__global__ void wmod_kernel_d(const float* __restrict__ w, double* __restrict__ wm,
                              int O, int C)
{
    int t = blockIdx.x * 256 + threadIdx.x;
    if (t >= O * C) return;
    int o = t / C, c = t - o * C;
    double a = (double)w[o * 2 * C + c];
    double b = (double)w[o * 2 * C + C + c];
    wm[o * C + c] = a;
    wm[(O + o) * C + c] = b - a;
}

__global__ void transpose_kernel(const float* __restrict__ in, float* __restrict__ out,
                                 int R, int C)
{
    long t = (long)blockIdx.x * 256 + threadIdx.x;
    if (t >= (long)R * C) return;
    int r = (int)(t / C), c = (int)(t - (long)r * C);
    out[(long)c * R + r] = in[t];
}

__global__ void transpose_bf(const float* __restrict__ in, unsigned short* __restrict__ out,
                             int R, int C)
{
    long t = (long)blockIdx.x * 256 + threadIdx.x;
    if (t >= (long)R * C) return;
    int r = (int)(t / C), c = (int)(t - (long)r * C);
    out[(long)c * R + r] = f2bf(in[t]);
}

// ---------------------------------------------------------------------------
// Single gather pass (P/Q split): stats + pre-BN max -> catOut. Unchanged.
// ---------------------------------------------------------------------------
__global__ __launch_bounds__(256) void edge_gather(const double* __restrict__ P,
                                                   const double* __restrict__ Q,
                                                   const int* __restrict__ idx,
                                                   int O, int shiftO,
                                                   double* __restrict__ sums,
                                                   double* __restrict__ catOut, int ldo)
{
    const int tid = threadIdx.x;
    const int o = tid & (O - 1);
    const int q = tid >> shiftO;
    const int nsub = 256 >> shiftO;
    const int lin = blockIdx.x;
    const int r0 = (lin & 7) * NP + (lin >> 3) * 16;   // XCD-batch swizzle
    double s = 0.0, ss = 0.0;
    for (int r = r0 + q; r < r0 + 16; r += nsub) {
        const double qv = Q[(size_t)r * O + o];
        const int* ip = idx + r * KNBR;
        double m = -INFINITY;
        for (int k = 0; k < KNBR; ++k) {
            const int j = ip[k];
            const double v = P[(size_t)j * O + o] + qv;
            s += v; ss = fma(v, v, ss);
            m = fmax(m, v);
        }
        catOut[(size_t)r * ldo + o] = m;
    }
    __shared__ double red[256];
    red[tid] = s; __syncthreads();
    if (q == 0) for (int qq = 1; qq < nsub; ++qq) s += red[o + (qq << shiftO)];
    __syncthreads();
    red[tid] = ss; __syncthreads();
    if (q == 0) {
        for (int qq = 1; qq < nsub; ++qq) ss += red[o + (qq << shiftO)];
        atomicAdd(&sums[o], s);
        atomicAdd(&sums[O + o], ss);
    }
}

__global__ void bn_finalize_d(const double* __restrict__ sums,
                              const float* __restrict__ g, const float* __restrict__ b,
                              double* __restrict__ ss, int O, double invCnt)
{
    int o = blockIdx.x * 256 + threadIdx.x;
    if (o >= O) return;
    double mu  = sums[o] * invCnt;
    double var = sums[O + o] * invCnt - mu * mu;
    double is  = 1.0 / sqrt(var + 1e-5);
    double sc  = (double)g[o] * is;
    ss[o] = sc;
    ss[O + o] = (double)b[o] - mu * sc;
}

__global__ __launch_bounds__(256) void bn_apply(double* __restrict__ catOut, int ldo,
                                                const double* __restrict__ ssb,
                                                int O, int shiftO,
                                                const double* __restrict__ P,
                                                const double* __restrict__ Q,
                                                const int* __restrict__ idx)
{
    const int t = blockIdx.x * 256 + threadIdx.x;
    const int o = t & (O - 1);
    const int r = t >> shiftO;
    const double sc = ssb[o], sh = ssb[O + o];
    double v = catOut[(size_t)r * ldo + o];
    if (sc < 0.0) {                       // rare path: min instead of max
        const double qv = Q[(size_t)r * O + o];
        const int* ip = idx + r * KNBR;
        double m = INFINITY;
        for (int k = 0; k < KNBR; ++k)
            m = fmin(m, P[(size_t)ip[k] * O + o] + qv);
        v = m;
    }
    double u = fma(v, sc, sh);
    u = u > 0.0 ? u : 0.2 * u;
    catOut[(size_t)r * ldo + o] = u;
}

// ---------------------------------------------------------------------------
__global__ void col_stats(const float* __restrict__ Y, int ncol,
                          float* __restrict__ sums)
{
    int c  = blockIdx.x * 128 + threadIdx.x;
    int r0 = blockIdx.y * 256;
    float s = 0.f, ss = 0.f;
    for (int r = r0; r < r0 + 256; ++r) {
        float v = Y[(long)r * ncol + c];
        s += v; ss = fmaf(v, v, ss);
    }
    atomicAdd(&sums[c], s);
    atomicAdd(&sums[ncol + c], ss);
}

__global__ void bn_finalize_f(const float* __restrict__ sums,
                              const float* __restrict__ g, const float* __restrict__ b,
                              float* __restrict__ ss, int O, float invCnt)
{
    int o = blockIdx.x * 256 + threadIdx.x;
    if (o >= O) return;
    float mu  = sums[o] * invCnt;
    float var = sums[O + o] * invCnt - mu * mu;
    float is  = rsqrtf(var + EPSV);
    float sc  = g[o] * is;
    ss[o] = sc;
    ss[O + o] = b[o] - mu * sc;
}

__global__ __launch_bounds__(256) void log_softmax_kernel(float* __restrict__ Y)
{
    const int lane = threadIdx.x & 63;
    const int row  = blockIdx.x * 4 + (threadIdx.x >> 6);
    float v = -INFINITY;
    if (lane < 50) v = Y[(long)row * 50 + lane];
    float mx = v;
#pragma unroll
    for (int off = 32; off >= 1; off >>= 1) mx = fmaxf(mx, __shfl_xor(mx, off, 64));
    float e = (lane < 50) ? expf(v - mx) : 0.f;
    float s = e;
#pragma unroll
    for (int off = 32; off >= 1; off >>= 1) s += __shfl_xor(s, off, 64);
    float l = logf(s) + mx;
    if (lane < 50) Y[(long)row * 50 + lane] = v - l;
}

// ===========================================================================
extern "C" void kernel_launch(void* const* d_in, const int* in_sizes, int n_in,
                              void* d_out, int out_size, void* d_ws, size_t ws_size,
                              hipStream_t stream)
{
    const float* x   = (const float*)d_in[0];
    const float* w[4]  = {(const float*)d_in[4], (const float*)d_in[7],
                          (const float*)d_in[10], (const float*)d_in[13]};
    const float* g[4]  = {(const float*)d_in[5], (const float*)d_in[8],
                          (const float*)d_in[11], (const float*)d_in[14]};
    const float* bb[4] = {(const float*)d_in[6], (const float*)d_in[9],
                          (const float*)d_in[12], (const float*)d_in[15]};
    const float* lw1 = (const float*)d_in[16]; const float* lb1 = (const float*)d_in[17];
    const float* lg1 = (const float*)d_in[18]; const float* lbb1 = (const float*)d_in[19];
    const float* mw1 = (const float*)d_in[20]; const float* mb1 = (const float*)d_in[21];
    const float* mg1 = (const float*)d_in[22]; const float* mbb1 = (const float*)d_in[23];
    const float* mw2 = (const float*)d_in[24]; const float* mb2 = (const float*)d_in[25];
    const float* mg2 = (const float*)d_in[26]; const float* mbb2 = (const float*)d_in[27];
    const float* hw  = (const float*)d_in[28]; const float* hb  = (const float*)d_in[29];
    float* out = (float*)d_out;

    // ---- workspace layout (bytes) ----
    char* base = (char*)d_ws;
    double* catD = (double*)base;                       // 64 MB
    char*  un    = base + 67108864;                     // 64 MB union region
    double* tmpv = (double*)un;                         // 16384*2*20*8 = 5.24 MB
    int*    tmpc = (int*)(un + 5242880);                // 2.62 MB (dead before PQ)
    double* Pb   = (double*)un;                         // P: up to 32 MB (after merge)
    double* Qb   = (double*)(un + 33554432);            // Q: up to 32 MB
    float* cat32 = (float*)un;                          // 32 MB (MLP phase)
    float* Y2    = (float*)(un + 33554432);             // 16 MB
    float* Y3    = (float*)(un + 50331648);             // 8 MB
    unsigned short* lw1Tb = (unsigned short*)(un + 58720256);  // 1 MB
    unsigned short* mw1Tb = (unsigned short*)(un + 59768832);  // 512 KB
    unsigned short* mw2Tb = (unsigned short*)(un + 60293120);  // 64 KB
    float* hwT   = (float*)(un + 60358656);             // 25.6 KB (fp32)
    float* Y1    = (float*)base;                        // aliases catD (dead after d2f)
    char* tail = base + 2u * 67108864u;
    int*    idxb  = (int*)tail;                         // 1.25 MB
    double* xD    = (double*)(tail + 1310720);          // 384 KB
    double* xxD   = (double*)(tail + 1703936);          // 128 KB
    double* wmodD = (double*)(tail + 1835008);          // 512 KB
    double* sumsD = (double*)(tail + 2359296);          // 8 KB
    double* ssbD  = (double*)(tail + 2367488);          // 8 KB
    float*  sumsF = (float*)(tail + 2375680);           // 8 KB
    float*  ssbF  = (float*)(tail + 2383872);           // 8 KB
    int*    mtab  = (int*)(tail + 2392064);             // 2.5 KB probe table

    // ---- fp64-MFMA layout probe (1 wave) ----
    mfma64_probe<<<1, 64, 0, stream>>>(mtab);

    // ---- x -> fp64 ----
    f2d_kernel<<<(NROWS * 3 + 255) / 256, 256, 0, stream>>>(x, xD, (long)NROWS * 3);

    // ---- 4 EdgeConv layers (all fp64) ----
    const double* Fin[4] = {xD, catD + 0, catD + 64, catD + 128};
    const int   ldaL[4] = {3, 512, 512, 512};
    const int   CL[4]   = {3, 64, 64, 128};
    const int   OL[4]   = {64, 64, 128, 256};
    const int   coff[4] = {0, 64, 128, 256};

    for (int l = 0; l < 4; ++l) {
        const double* F = Fin[l];
        const int lda = ldaL[l], C = CL[l], O = OL[l];
        const int shiftO = (O == 64) ? 6 : (O == 128) ? 7 : 8;

        wmod_kernel_d<<<(O * C + 255) / 256, 256, 0, stream>>>(w[l], wmodD, O, C);
        xx_kernel_d<<<NROWS / 256, 256, 0, stream>>>(F, lda, C, xxD);

        // fused dist + top-20 (no D materialization), then half-merge
        dim3 kg(NP / 64, 2, NB);
        if (C == 3)
            knn_fused2<4><<<kg, 256, 0, stream>>>(F, lda, C, xxD, tmpv, tmpc, mtab);
        else if (C == 64)
            knn_fused2<64><<<kg, 256, 0, stream>>>(F, lda, C, xxD, tmpv, tmpc, mtab);
        else
            knn_fused2<128><<<kg, 256, 0, stream>>>(F, lda, C, xxD, tmpv, tmpc, mtab);
        merge_topk<<<NROWS / 256, 256, 0, stream>>>(tmpv, tmpc, idxb);

        gemm64<<<dim3((2 * O) / 64, NROWS / 128), 256, 0, stream>>>(
            F, lda, wmodD, C, Pb, Qb, O, C, mtab);

        hipMemsetAsync(sumsD, 0, 2 * O * sizeof(double), stream);
        edge_gather<<<NROWS / 16, 256, 0, stream>>>(Pb, Qb, idxb, O, shiftO, sumsD,
                                                    catD + coff[l], 512);
        bn_finalize_d<<<(O + 255) / 256, 256, 0, stream>>>(sumsD, g[l], bb[l], ssbD, O,
                                                           1.0 / ((double)NROWS * KNBR));
        bn_apply<<<(NROWS * O) / 256, 256, 0, stream>>>(catD + coff[l], 512, ssbD,
                                                        O, shiftO, Pb, Qb, idxb);
    }

    // ---- cat fp64 -> fp32 (catD region becomes free -> Y1) ----
    d2f_kernel<<<((long)NROWS * 512 + 255) / 256, 256, 0, stream>>>(catD, cat32, (long)NROWS * 512);

    // ---- weight transposes (MLP -> bf16, head -> fp32) ----
    transpose_bf<<<(512 * 1024 + 255) / 256, 256, 0, stream>>>(lw1, lw1Tb, 512, 1024);
    transpose_bf<<<(1024 * 256 + 255) / 256, 256, 0, stream>>>(mw1, mw1Tb, 1024, 256);
    transpose_bf<<<(256 * 128 + 255) / 256, 256, 0, stream>>>(mw2, mw2Tb, 256, 128);
    transpose_kernel<<<(128 * 50 + 255) / 256, 256, 0, stream>>>(hw, hwT, 128, 50);

    // ---- MLP: bf16 MFMA GEMMs, fp32 accumulate ----
    {
        gemm_bf16<<<dim3(1024 / 128, NROWS / 64), 256, 0, stream>>>(
            cat32, 512, lw1Tb, Y1, 1024, 512, lb1, nullptr);
        hipMemsetAsync(sumsF, 0, 2 * 1024 * sizeof(float), stream);
        col_stats<<<dim3(1024 / 128, 64), 128, 0, stream>>>(Y1, 1024, sumsF);
        bn_finalize_f<<<4, 256, 0, stream>>>(sumsF, lg1, lbb1, ssbF, 1024, 1.f / NROWS);
    }
    {
        gemm_bf16<<<dim3(256 / 128, NROWS / 64), 256, 0, stream>>>(
            Y1, 1024, mw1Tb, Y2, 256, 1024, mb1, ssbF);
        hipMemsetAsync(sumsF, 0, 2 * 256 * sizeof(float), stream);
        col_stats<<<dim3(256 / 128, 64), 128, 0, stream>>>(Y2, 256, sumsF);
        bn_finalize_f<<<1, 256, 0, stream>>>(sumsF, mg1, mbb1, ssbF, 256, 1.f / NROWS);
    }
    {
        gemm_bf16<<<dim3(128 / 128, NROWS / 64), 256, 0, stream>>>(
            Y2, 256, mw2Tb, Y3, 128, 256, mb2, ssbF);
        hipMemsetAsync(sumsF, 0, 2 * 128 * sizeof(float), stream);
        col_stats<<<dim3(1, 64), 128, 0, stream>>>(Y3, 128, sumsF);
        bn_finalize_f<<<1, 256, 0, stream>>>(sumsF, mg2, mbb2, ssbF, 128, 1.f / NROWS);
    }
    {
        dim3 gg(1, NROWS / 128);
        gemm_f32<<<gg, 256, 0, stream>>>(Y3, 128, hwT, 128, out, 50,
                                         NROWS, 50, 128, 3, hb, ssbF);
        log_softmax_kernel<<<NROWS / 4, 256, 0, stream>>>(out);
    }
}